// Round 1
// baseline (282.820 us; speedup 1.0000x reference)
//
#include <hip/hip_runtime.h>
#include <hip/hip_bf16.h>

// Problem constants: B=2, C=512, H=W=64 -> N=4096, G=32 (16 ch/group), EPS=1e-6.

typedef float f32x4 __attribute__((ext_vector_type(4)));
typedef __bf16 bf16x8 __attribute__((ext_vector_type(8)));

typedef const __attribute__((address_space(1))) unsigned char* gas_p;
typedef __attribute__((address_space(3))) unsigned char* las_p;

__device__ __forceinline__ void gload_lds16(const void* g, void* l) {
  // async DMA: each lane contributes 16B; LDS dst = wave-uniform base + lane*16
  __builtin_amdgcn_global_load_lds((gas_p)g, (las_p)l, 16, 0, 0);
}

// ====== prelude: weight cvt (4x1024 blocks) | gn_stats (64) | bcat (1) ======
__global__ __launch_bounds__(256) void prelude_k(
    const float* __restrict__ wq, const float* __restrict__ wk,
    const float* __restrict__ wv, const float* __restrict__ wo,
    __hip_bfloat16* __restrict__ wqkb, __hip_bfloat16* __restrict__ wvb,
    __hip_bfloat16* __restrict__ wob, const float* __restrict__ bq,
    const float* __restrict__ bk, float* __restrict__ bqk,
    const float* __restrict__ x, float* __restrict__ stats) {
  int bid = blockIdx.x;
  if (bid < 4096) {
    const float* src;
    __hip_bfloat16* dst;
    if (bid < 1024)      { src = wq; dst = wqkb; }
    else if (bid < 2048) { src = wk; dst = wqkb + 262144; }
    else if (bid < 3072) { src = wv; dst = wvb; }
    else                 { src = wo; dst = wob; }
    int i = (bid & 1023) * 256 + threadIdx.x;  // 1024*256 = 262144 = 512*512
    dst[i] = __float2bfloat16(src[i]);
    return;
  }
  if (bid < 4160) {  // gn_stats: one block per (b,g)
    int bg = bid - 4096;
    const float4* p = (const float4*)(x + (size_t)bg * 65536);
    float s = 0.f, s2 = 0.f;
    for (int i = threadIdx.x; i < 16384; i += 256) {
      float4 v = p[i];
      s  += v.x + v.y + v.z + v.w;
      s2 += v.x * v.x + v.y * v.y + v.z * v.z + v.w * v.w;
    }
#pragma unroll
    for (int off = 32; off > 0; off >>= 1) {
      s  += __shfl_xor(s, off);
      s2 += __shfl_xor(s2, off);
    }
    __shared__ float rs[4], rs2[4];
    int wid = threadIdx.x >> 6, lane = threadIdx.x & 63;
    if (lane == 0) { rs[wid] = s; rs2[wid] = s2; }
    __syncthreads();
    if (threadIdx.x == 0) {
      float S  = rs[0] + rs[1] + rs[2] + rs[3];
      float S2 = rs2[0] + rs2[1] + rs2[2] + rs2[3];
      float mean = S * (1.f / 65536.f);
      float var  = S2 * (1.f / 65536.f) - mean * mean;
      stats[bg * 2]     = mean;
      stats[bg * 2 + 1] = rsqrtf(var + 1e-6f);
    }
    return;
  }
  // bcat
  for (int j = threadIdx.x; j < 1024; j += 256)
    bqk[j] = (j < 512) ? bq[j] : bk[j - 512];
}

// ------- GroupNorm apply + transpose, vectorized: x fp32 -> hf bf16 [b][n][c]
__global__ __launch_bounds__(256) void gn_apply_k(const float* __restrict__ x,
                                                  const float* __restrict__ stats,
                                                  const float* __restrict__ gw,
                                                  const float* __restrict__ gb,
                                                  __hip_bfloat16* __restrict__ hf) {
  int c0 = blockIdx.x * 64, n0 = blockIdx.y * 64, b = blockIdx.z;
  __shared__ float tile[64][65];
  int tid = threadIdx.x;
  int cl = tid >> 2, q = tid & 3;
  int c = c0 + cl;
  float mean = stats[(b * 32 + (c >> 4)) * 2];
  float rstd = stats[(b * 32 + (c >> 4)) * 2 + 1];
  float sc = rstd * gw[c];
  float sh = gb[c] - mean * sc;
  const float* xr = x + ((size_t)(b * 512 + c0 + cl)) * 4096 + n0 + q * 16;
#pragma unroll
  for (int j = 0; j < 4; j++) {
    float4 v = *(const float4*)(xr + 4 * j);
    int n = q * 16 + 4 * j;
    tile[cl][n]     = v.x * sc + sh;
    tile[cl][n + 1] = v.y * sc + sh;
    tile[cl][n + 2] = v.z * sc + sh;
    tile[cl][n + 3] = v.w * sc + sh;
  }
  __syncthreads();
  int nl = tid >> 2, ch = q * 16;
  bf16x8 o0, o1;
#pragma unroll
  for (int l = 0; l < 8; l++) {
    o0[l] = (__bf16)tile[ch + l][nl];
    o1[l] = (__bf16)tile[ch + 8 + l][nl];
  }
  __hip_bfloat16* op = hf + ((size_t)(b * 4096 + n0 + nl)) * 512 + c0 + ch;
  *(uint4*)op = *(uint4*)&o0;
  *(uint4*)(op + 8) = *(uint4*)&o1;
}

// ============ fused QKV (double-buffered DMA + LDS epilogue) ============
// bx<8 : QK GEMM  qk[t][o] (o<1024) = sum_c hf[t][c]*Wqk[o][c] + bqk[o]
// bx>=8: V GEMM   vT[b][o][t]       = sum_c Wv[o][c]*hf[t][c] + bv[o]
__global__ __launch_bounds__(256, 4) void qkv_k(
    const __hip_bfloat16* __restrict__ hf, const __hip_bfloat16* __restrict__ wqk,
    const __hip_bfloat16* __restrict__ wv, const float* __restrict__ bqk,
    const float* __restrict__ bv, __hip_bfloat16* __restrict__ qk,
    __hip_bfloat16* __restrict__ vT) {
  bool isV = blockIdx.x >= 8;
  int m0 = isV ? (blockIdx.x - 8) * 128 : blockIdx.y * 128;
  int n0 = isV ? blockIdx.y * 128 : blockIdx.x * 128;
  const __hip_bfloat16* A  = isV ? wv : hf;   // [m][512]
  const __hip_bfloat16* Bm = isV ? hf : wqk;  // [n][512]

  __shared__ __align__(16) unsigned char smem[34816];  // dbuf(32K) | epi(34K)
  __hip_bfloat16* As  = (__hip_bfloat16*)smem;
  __hip_bfloat16* Bs  = As + 8192;
  __hip_bfloat16* epi = (__hip_bfloat16*)smem;         // [128][136]

  int tid  = threadIdx.x;
  int wvx  = tid >> 6, lane = tid & 63;
  int wr   = (wvx >> 1) * 64, wc = (wvx & 1) * 64;
  int quad = lane >> 4, l16 = lane & 15;

  int srow = wvx * 32 + (lane >> 2);
  int scol = (lane & 3) * 8;
  const __hip_bfloat16* gA0 = A  + (size_t)(m0 + srow) * 512 + scol;
  const __hip_bfloat16* gA1 = gA0 + (size_t)16 * 512;
  const __hip_bfloat16* gB0 = Bm + (size_t)(n0 + srow) * 512 + scol;
  const __hip_bfloat16* gB1 = gB0 + (size_t)16 * 512;

  auto stage = [&](int kk, int bsel) {
    int lb = bsel * 4096 + wvx * 1024;
    gload_lds16(gA0 + kk, &As[lb]);
    gload_lds16(gA1 + kk, &As[lb + 512]);
    gload_lds16(gB0 + kk, &Bs[lb]);
    gload_lds16(gB1 + kk, &Bs[lb + 512]);
  };

  f32x4 acc[4][4] = {};
  stage(0, 0);
  for (int kt = 0; kt < 16; kt++) {
    __syncthreads();
    if (kt + 1 < 16) stage((kt + 1) << 5, (kt + 1) & 1);
    const __hip_bfloat16* Ab = &As[(kt & 1) * 4096];
    const __hip_bfloat16* Bb = &Bs[(kt & 1) * 4096];
    bf16x8 af[4], bfr[4];
#pragma unroll
    for (int i = 0; i < 4; i++)
      af[i] = *(const bf16x8*)&Ab[(wr + i * 16 + l16) * 32 + quad * 8];
#pragma unroll
    for (int j = 0; j < 4; j++)
      bfr[j] = *(const bf16x8*)&Bb[(wc + j * 16 + l16) * 32 + quad * 8];
#pragma unroll
    for (int i = 0; i < 4; i++)
#pragma unroll
      for (int j = 0; j < 4; j++)
        acc[i][j] = __builtin_amdgcn_mfma_f32_16x16x32_bf16(af[i], bfr[j],
                                                            acc[i][j], 0, 0, 0);
  }

  // ---- epilogue via LDS: C-layout -> row-major coalesced ----
  float bj[4], bm[4][4];
  if (!isV) {
#pragma unroll
    for (int j = 0; j < 4; j++) bj[j] = bqk[n0 + wc + j * 16 + l16];
  } else {
#pragma unroll
    for (int i = 0; i < 4; i++)
#pragma unroll
      for (int r = 0; r < 4; r++)
        bm[i][r] = bv[m0 + wr + i * 16 + quad * 4 + r];
  }
  __syncthreads();  // dbuf fragment reads done before epi overwrite
#pragma unroll
  for (int i = 0; i < 4; i++)
#pragma unroll
    for (int j = 0; j < 4; j++)
#pragma unroll
      for (int r = 0; r < 4; r++) {
        int ml = wr + i * 16 + quad * 4 + r;
        int nl = wc + j * 16 + l16;
        float v = acc[i][j][r] + (isV ? bm[i][r] : bj[j]);
        epi[ml * 136 + nl] = __float2bfloat16(v);
      }
  __syncthreads();
  int mr = tid >> 1, h = tid & 1;
  const __hip_bfloat16* rowp = &epi[mr * 136 + h * 64];
  if (!isV) {
    __hip_bfloat16* o = qk + (size_t)(m0 + mr) * 1024 + n0 + h * 64;
#pragma unroll
    for (int c = 0; c < 8; c++)
      *(uint4*)(o + c * 8) = *(const uint4*)(rowp + c * 8);
  } else {
    int b = (n0 + h * 64) >> 12, t = (n0 + h * 64) & 4095;
    __hip_bfloat16* o = vT + ((size_t)(b * 512 + m0 + mr)) * 4096 + t;
#pragma unroll
    for (int c = 0; c < 8; c++)
      *(uint4*)(o + c * 8) = *(const uint4*)(rowp + c * 8);
  }
}

// ============ fused attention: exp(QK^T*scale) -> P (LDS) -> P*V ============
// Never materializes S in HBM. Work = (b, kv-split of 2048, q-tile of 64).
// Per kv-tile of 128: S = Q K^T over d=512 (8 dbuf BK=64 stages, pv_k-style
// XOR-swizzled DMA), exp + reg rowsum, P bf16 -> LDS [64][136], then PV in 4
// ping-ponged kv-sub=32 V-slab stages (vT rows are the MFMA B operand).
// O accumulates in f32 regs across the whole 2048-kv range (64 f32/thread).
// Writes unnormalized partials + per-row expsums; reduce2_k folds 2 splits.
__global__ __launch_bounds__(512, 2) void attn_k(
    const __hip_bfloat16* __restrict__ qk, const __hip_bfloat16* __restrict__ vT,
    __hip_bfloat16* __restrict__ part, float* __restrict__ rsum) {
  const float scale = 0.044194173824159216f;
  // XCD grouping: (b,spl) -> 2 dedicated XCDs so K/V (4MB) stays L2-resident
  int bid = blockIdx.x;
  int g2 = bid & 7;
  int b = g2 >> 2, spl = (g2 >> 1) & 1;
  int qtile = (g2 & 1) * 32 + (bid >> 3);  // 0..63

  const __hip_bfloat16* qkb = qk + (size_t)b * 4194304;
  const __hip_bfloat16* vTb = vT + (size_t)b * 2097152;

  __shared__ __align__(16) unsigned char smem[133120];
  __hip_bfloat16* Qs = (__hip_bfloat16*)smem;             // 2 x [64][64]
  __hip_bfloat16* Ks = (__hip_bfloat16*)(smem + 16384);   // 2 x [128][64]
  __hip_bfloat16* Vs = (__hip_bfloat16*)(smem + 49152);   // 2 x [512][32]
  __hip_bfloat16* Ps = (__hip_bfloat16*)(smem + 114688);  // [64][136]
  float* Rs = (float*)(smem + 132096);                    // [4][64]

  int tid = threadIdx.x, wv = tid >> 6, lane = tid & 63;
  int quad = lane >> 4, l16 = lane & 15;
  int q0 = (wv >> 2) * 32;    // wave q-rows (QK and PV)
  int kvc0 = (wv & 3) * 32;   // wave kv-cols (QK)
  int wd0 = (wv & 3) * 128;   // wave d-cols (PV)

  // QK staging: rows of 64 elems (128B), 8 rows/inst, XOR chunk swizzle
  // LDS[r][c] = G[r][c ^ (r&7)] (16B chunks) -> b128 frag reads spread banks
  int srow8 = lane >> 3;
  int schk = ((lane & 7) ^ srow8) * 8;
  const __hip_bfloat16* gQ = qkb + (size_t)(qtile * 64 + wv * 8 + srow8) * 1024 + schk;
  const __hip_bfloat16* gK0 =
      qkb + (size_t)(spl * 2048 + wv * 16 + srow8) * 1024 + 512 + schk;
  const __hip_bfloat16* gK1 = gK0 + (size_t)8 * 1024;
  // V staging: rows of 32 elems (64B), 16 rows/inst, linear
  const __hip_bfloat16* gV = vTb + (size_t)(wv * 64 + (lane >> 2)) * 4096 +
                             spl * 2048 + (lane & 3) * 8;

  auto stageQK = [&](int t, int s, int bsel) {
    int koff = t * 131072 + s * 64;  // t*128 rows + s*64 cols
    gload_lds16(gQ + s * 64, &Qs[bsel * 4096 + wv * 512]);
    gload_lds16(gK0 + koff, &Ks[bsel * 8192 + wv * 1024]);
    gload_lds16(gK1 + koff, &Ks[bsel * 8192 + wv * 1024 + 512]);
  };
  auto stageV = [&](int t, int sub, int vb) {
    const __hip_bfloat16* g = gV + t * 128 + sub * 32;
#pragma unroll
    for (int c = 0; c < 4; c++)
      gload_lds16(g + (size_t)(c * 16) * 4096, &Vs[vb * 16384 + wv * 2048 + c * 512]);
  };

  f32x4 accS[2][2] = {};
  f32x4 accO[8][2] = {};
  float rsr[8] = {};

  stageQK(0, 0, 0);
  for (int t = 0; t < 16; t++) {
    // ---- QK^T: accumulate S over d=512 in 8 BK=64 stages ----
    for (int s = 0; s < 8; s++) {
      __syncthreads();  // drains prev stage DMA; guards dbuf overwrite
      if (s < 7) stageQK(t, s + 1, (s + 1) & 1);
      else stageV(t, 0, 0);  // prefetch first V slab under exp phase
      const __hip_bfloat16* Qb = &Qs[(s & 1) * 4096];
      const __hip_bfloat16* Kb = &Ks[(s & 1) * 8192];
      bf16x8 aq[2][2], bkf[2][2];
#pragma unroll
      for (int ii = 0; ii < 2; ii++)
#pragma unroll
        for (int kk = 0; kk < 2; kk++) {
          int r = q0 + ii * 16 + l16;
          aq[ii][kk] = *(const bf16x8*)&Qb[r * 64 + ((kk * 4 + quad) ^ (r & 7)) * 8];
        }
#pragma unroll
      for (int jj = 0; jj < 2; jj++)
#pragma unroll
        for (int kk = 0; kk < 2; kk++) {
          int r = kvc0 + jj * 16 + l16;
          bkf[jj][kk] = *(const bf16x8*)&Kb[r * 64 + ((kk * 4 + quad) ^ (r & 7)) * 8];
        }
#pragma unroll
      for (int ii = 0; ii < 2; ii++)
#pragma unroll
        for (int jj = 0; jj < 2; jj++)
#pragma unroll
          for (int kk = 0; kk < 2; kk++)
            accS[ii][jj] = __builtin_amdgcn_mfma_f32_16x16x32_bf16(
                aq[ii][kk], bkf[jj][kk], accS[ii][jj], 0, 0, 0);
    }
    // ---- exp + rowsum, P -> LDS (disjoint per-wave tiles, no race) ----
#pragma unroll
    for (int ii = 0; ii < 2; ii++)
#pragma unroll
      for (int jj = 0; jj < 2; jj++) {
#pragma unroll
        for (int rr = 0; rr < 4; rr++) {
          float p = __expf(accS[ii][jj][rr] * scale);
          rsr[ii * 4 + rr] += p;
          Ps[(q0 + ii * 16 + quad * 4 + rr) * 136 + kvc0 + jj * 16 + l16] =
              __float2bfloat16(p);
        }
        accS[ii][jj] = (f32x4){0.f, 0.f, 0.f, 0.f};
      }
    // ---- PV: O += P * V over this kv-tile, 4 kv-sub=32 stages ----
    for (int sub = 0; sub < 4; sub++) {
      __syncthreads();  // P visible (sub0) / drains V stage; guards ping-pong
      if (sub < 3) stageV(t, sub + 1, (sub + 1) & 1);
      else if (t + 1 < 16) stageQK(t + 1, 0, 0);
      const __hip_bfloat16* Vb = &Vs[(sub & 1) * 16384];
      bf16x8 pa[2], bvf[8];
#pragma unroll
      for (int ii = 0; ii < 2; ii++) {
        int r = q0 + ii * 16 + l16;
        pa[ii] = *(const bf16x8*)&Ps[r * 136 + sub * 32 + quad * 8];
      }
#pragma unroll
      for (int jj = 0; jj < 8; jj++) {
        int r = wd0 + jj * 16 + l16;
        bvf[jj] = *(const bf16x8*)&Vb[r * 32 + quad * 8];
      }
#pragma unroll
      for (int jj = 0; jj < 8; jj++)
#pragma unroll
        for (int ii = 0; ii < 2; ii++)
          accO[jj][ii] = __builtin_amdgcn_mfma_f32_16x16x32_bf16(
              pa[ii], bvf[jj], accO[jj][ii], 0, 0, 0);
    }
  }

  // ---- epilogue: partials (bf16) + per-row expsum ----
  size_t pbase = ((size_t)(spl * 2 + b) * 4096 + qtile * 64) * 512;
#pragma unroll
  for (int ii = 0; ii < 2; ii++)
#pragma unroll
    for (int rr = 0; rr < 4; rr++) {
      int row = q0 + ii * 16 + quad * 4 + rr;
#pragma unroll
      for (int jj = 0; jj < 8; jj++)
        part[pbase + (size_t)row * 512 + wd0 + jj * 16 + l16] =
            __float2bfloat16(accO[jj][ii][rr]);
    }
#pragma unroll
  for (int k = 0; k < 8; k++)
#pragma unroll
    for (int off = 1; off < 16; off <<= 1) rsr[k] += __shfl_xor(rsr[k], off);
  if (l16 == 0) {
#pragma unroll
    for (int ii = 0; ii < 2; ii++)
#pragma unroll
      for (int rr = 0; rr < 4; rr++)
        Rs[(wv & 3) * 64 + q0 + ii * 16 + quad * 4 + rr] = rsr[ii * 4 + rr];
  }
  __syncthreads();
  if (tid < 64)
    rsum[spl * 8192 + b * 4096 + qtile * 64 + tid] =
        Rs[tid] + Rs[64 + tid] + Rs[128 + tid] + Rs[192 + tid];
}

// ---- fold 2 kv-split partials + expsums, normalize -> obuf ----
__global__ __launch_bounds__(256) void reduce2_k(
    const __hip_bfloat16* __restrict__ part, const float* __restrict__ rsum,
    __hip_bfloat16* __restrict__ obuf) {
  size_t i8 = (size_t)blockIdx.x * 256 + threadIdx.x;
  size_t perb = 262144;  // 4096*512/8 vectors per batch
  size_t b = i8 / perb, r = i8 - b * perb;
  int t = (int)(r >> 6);
  float ps = rsum[b * 4096 + t] + rsum[8192 + b * 4096 + t];
  float inv = 1.f / ps;
  bf16x8 v0 = ((const bf16x8*)part)[b * perb + r];
  bf16x8 v1 = ((const bf16x8*)part)[(2 + b) * perb + r];
  bf16x8 o;
#pragma unroll
  for (int l = 0; l < 8; l++)
    o[l] = (__bf16)(((float)v0[l] + (float)v1[l]) * inv);
  ((bf16x8*)obuf)[b * perb + r] = o;
}

// ====== out-proj, 64x128 tiles (512 blocks = 2/CU vs old 256 = 1/CU) ======
// out[b][c][t] = x[b][c][t] + bf16(sum_o Wo[c][o]*obuf[b][t][o] + bo[c])
__global__ __launch_bounds__(256, 2) void oproj_k(
    const __hip_bfloat16* __restrict__ Wo, const __hip_bfloat16* __restrict__ O,
    float* __restrict__ out, const float* __restrict__ bias,
    const float* __restrict__ resid) {
  int m0 = blockIdx.y * 64, n0 = blockIdx.x * 128, bb = blockIdx.z;
  O += (size_t)bb * 4096 * 512;
  size_t cbase = (size_t)bb * 512 * 4096;

  __shared__ __align__(16) unsigned char smem[24576];  // A 2x4K | B 2x8K; epi
  __hip_bfloat16* As  = (__hip_bfloat16*)smem;          // 2 x [64][32]
  __hip_bfloat16* Bs  = As + 4096;                      // 2 x [128][32]
  __hip_bfloat16* epi = (__hip_bfloat16*)smem;          // [64][136] = 17.4K

  int tid = threadIdx.x, wv = tid >> 6, lane = tid & 63;
  int wr = (wv >> 1) * 32, wc = (wv & 1) * 64;
  int quad = lane >> 4, l16 = lane & 15;

  int lr = lane >> 2, scol = (lane & 3) * 8;
  const __hip_bfloat16* gA  = Wo + (size_t)(m0 + wv * 16 + lr) * 512 + scol;
  const __hip_bfloat16* gB0 = O  + (size_t)(n0 + wv * 32 + lr) * 512 + scol;
  const __hip_bfloat16* gB1 = gB0 + (size_t)16 * 512;

  auto stage = [&](int kk, int bsel) {
    gload_lds16(gA + kk, &As[bsel * 2048 + wv * 512]);
    gload_lds16(gB0 + kk, &Bs[bsel * 4096 + wv * 1024]);
    gload_lds16(gB1 + kk, &Bs[bsel * 4096 + wv * 1024 + 512]);
  };

  f32x4 acc[2][4] = {};
  stage(0, 0);
  for (int kt = 0; kt < 16; kt++) {
    __syncthreads();
    if (kt + 1 < 16) stage((kt + 1) << 5, (kt + 1) & 1);
    const __hip_bfloat16* Ab = &As[(kt & 1) * 2048];
    const __hip_bfloat16* Bb = &Bs[(kt & 1) * 4096];
    bf16x8 af[2], bfr[4];
#pragma unroll
    for (int i = 0; i < 2; i++)
      af[i] = *(const bf16x8*)&Ab[(wr + i * 16 + l16) * 32 + quad * 8];
#pragma unroll
    for (int j = 0; j < 4; j++)
      bfr[j] = *(const bf16x8*)&Bb[(wc + j * 16 + l16) * 32 + quad * 8];
#pragma unroll
    for (int i = 0; i < 2; i++)
#pragma unroll
      for (int j = 0; j < 4; j++)
        acc[i][j] = __builtin_amdgcn_mfma_f32_16x16x32_bf16(af[i], bfr[j],
                                                            acc[i][j], 0, 0, 0);
  }

  float pre[2][4];
#pragma unroll
  for (int i = 0; i < 2; i++)
#pragma unroll
    for (int r = 0; r < 4; r++)
      pre[i][r] = bias[m0 + wr + i * 16 + quad * 4 + r];
  __syncthreads();
#pragma unroll
  for (int i = 0; i < 2; i++)
#pragma unroll
    for (int j = 0; j < 4; j++)
#pragma unroll
      for (int r = 0; r < 4; r++)
        epi[(wr + i * 16 + quad * 4 + r) * 136 + wc + j * 16 + l16] =
            __float2bfloat16(acc[i][j][r] + pre[i][r]);
  __syncthreads();
  int mr = tid >> 2, seg = tid & 3;  // 4 threads/row, 32 elems each
  const __hip_bfloat16* rowp = &epi[mr * 136 + seg * 32];
  size_t obase = cbase + (size_t)(m0 + mr) * 4096 + n0 + seg * 32;
#pragma unroll
  for (int c = 0; c < 4; c++) {
    bf16x8 val = *(const bf16x8*)(rowp + c * 8);
    size_t idx = obase + c * 8;
    float4 r0 = *(const float4*)&resid[idx];
    float4 r1 = *(const float4*)&resid[idx + 4];
    float4 o0, o1;
    o0.x = r0.x + (float)val[0]; o0.y = r0.y + (float)val[1];
    o0.z = r0.z + (float)val[2]; o0.w = r0.w + (float)val[3];
    o1.x = r1.x + (float)val[4]; o1.y = r1.y + (float)val[5];
    o1.z = r1.z + (float)val[6]; o1.w = r1.w + (float)val[7];
    *(float4*)&out[idx] = o0;
    *(float4*)&out[idx + 4] = o1;
  }
}

extern "C" void kernel_launch(void* const* d_in, const int* in_sizes, int n_in,
                              void* d_out, int out_size, void* d_ws,
                              size_t ws_size, hipStream_t stream) {
  const float* xp  = (const float*)d_in[0];
  const float* gwp = (const float*)d_in[1];
  const float* gbp = (const float*)d_in[2];
  const float* wqp = (const float*)d_in[3];
  const float* bqp = (const float*)d_in[4];
  const float* wkp = (const float*)d_in[5];
  const float* bkp = (const float*)d_in[6];
  const float* wvp = (const float*)d_in[7];
  const float* bvp = (const float*)d_in[8];
  const float* wop = (const float*)d_in[9];
  const float* bop = (const float*)d_in[10];
  float* outp = (float*)d_out;

  char* w = (char*)d_ws;
  size_t off = 0;
  auto alloc = [&](size_t bytes) {
    void* p = w + off;
    off += (bytes + 255) & ~(size_t)255;
    return p;
  };
  float* stats         = (float*)alloc(64 * 2 * sizeof(float));
  __hip_bfloat16* hf   = (__hip_bfloat16*)alloc((size_t)2 * 4096 * 512 * 2);
  __hip_bfloat16* wqkb = (__hip_bfloat16*)alloc((size_t)1024 * 512 * 2);
  __hip_bfloat16* wvb  = (__hip_bfloat16*)alloc((size_t)512 * 512 * 2);
  __hip_bfloat16* wob  = (__hip_bfloat16*)alloc((size_t)512 * 512 * 2);
  float* bqk           = (float*)alloc(1024 * sizeof(float));
  float* rsum          = (float*)alloc((size_t)2 * 2 * 4096 * sizeof(float));
  __hip_bfloat16* qk   = (__hip_bfloat16*)alloc((size_t)2 * 4096 * 1024 * 2);
  __hip_bfloat16* vT   = (__hip_bfloat16*)alloc((size_t)2 * 512 * 4096 * 2);
  __hip_bfloat16* obuf = (__hip_bfloat16*)alloc((size_t)2 * 4096 * 512 * 2);
  __hip_bfloat16* part = (__hip_bfloat16*)alloc((size_t)4 * 4096 * 512 * 2);

  // prelude: 4096 cvt blocks + 64 gn_stats blocks + 1 bcat block
  prelude_k<<<4161, 256, 0, stream>>>(wqp, wkp, wvp, wop, wqkb, wvb, wob,
                                      bqp, bkp, bqk, xp, stats);

  gn_apply_k<<<dim3(8, 64, 2), 256, 0, stream>>>(xp, stats, gwp, gbp, hf);

  // fused QKV: qk[8192][1024] and vT[2][512][4096]
  qkv_k<<<dim3(12, 64, 1), 256, 0, stream>>>(hf, wqkb, wvb, bqk, bvp, qk, vT);

  // fused attention: S never hits HBM; partials [2spl][2b][4096][512] + rsum
  attn_k<<<256, 512, 0, stream>>>(qk, vT, part, rsum);

  // fold 2 partials + expsums, normalize -> obuf
  reduce2_k<<<2048, 256, 0, stream>>>(part, rsum, obuf);

  // out[b][c][t] = x + Wo*O + bo  (64x128 tiles, 512 blocks)
  oproj_k<<<dim3(32, 8, 2), 256, 0, stream>>>(wob, obuf, outp, bop, xp);
}